// Round 15
// baseline (708.780 us; speedup 1.0000x reference)
//
#include <hip/hip_runtime.h>
#include <math.h>

#define NEG_ATT 0.2f
#define NEG 0.01f

typedef __attribute__((ext_vector_type(8))) short short8;
typedef __attribute__((ext_vector_type(4))) float f32x4;
typedef __attribute__((ext_vector_type(2))) float f32x2;

static __device__ __forceinline__ float lrelu(float x, float s) { return x > 0.f ? x : s * x; }
static __device__ __forceinline__ unsigned short f2b(float f) {
  union { float f; unsigned int i; } v; v.f = f;
  unsigned int r = (v.i + 0x7fffu + ((v.i >> 16) & 1u)) >> 16;
  return (unsigned short)r;
}
// unpack uint4 (8 bf16) -> 4 float2 pairs
static __device__ __forceinline__ void up2x4(uint4 r, f32x2* v) {
  union { unsigned int i; float f; } t;
  t.i = r.x << 16;          v[0].x = t.f;
  t.i = r.x & 0xffff0000u;  v[0].y = t.f;
  t.i = r.y << 16;          v[1].x = t.f;
  t.i = r.y & 0xffff0000u;  v[1].y = t.f;
  t.i = r.z << 16;          v[2].x = t.f;
  t.i = r.z & 0xffff0000u;  v[2].y = t.f;
  t.i = r.w << 16;          v[3].x = t.f;
  t.i = r.w & 0xffff0000u;  v[3].y = t.f;
}

// ---------------- CSR build ----------------
__global__ void hist_kernel(const int* __restrict__ dst, int* __restrict__ cnt, int E, int N) {
  int i = blockIdx.x * blockDim.x + threadIdx.x;
  int tot = E + N;
  if (i >= tot) return;
  int d = (i < E) ? dst[i] : (i - E);
  atomicAdd(&cnt[d], 1);
}

// two-phase parallel exclusive scan over n counts
__global__ void scan1_kernel(const int* __restrict__ cnt, int* __restrict__ rowptr,
                             int* __restrict__ bsum, int n) {
  __shared__ int wsum[16];
  int t = threadIdx.x, lane = t & 63, wv = t >> 6;
  int i = blockIdx.x * 1024 + t;
  int orig = (i < n) ? cnt[i] : 0;
  int v = orig;
  #pragma unroll
  for (int off = 1; off < 64; off <<= 1) {
    int u = __shfl_up(v, off);
    if (lane >= off) v += u;
  }
  if (lane == 63) wsum[wv] = v;
  __syncthreads();
  if (t < 16) {
    int s = wsum[t];
    #pragma unroll
    for (int off = 1; off < 16; off <<= 1) {
      int u = __shfl_up(s, off);
      if (t >= off) s += u;
    }
    wsum[t] = s;
  }
  __syncthreads();
  int waveoff = (wv > 0) ? wsum[wv - 1] : 0;
  if (i < n) rowptr[i] = waveoff + v - orig;   // exclusive within block
  if (t == 1023) bsum[blockIdx.x] = wsum[15];
}

__global__ void scan2_kernel(int* __restrict__ rowptr, int* __restrict__ cursor,
                             const int* __restrict__ bsum, int n) {
  int t = threadIdx.x, b = blockIdx.x;
  int off = 0;
  for (int k = 0; k < b; ++k) off += bsum[k];
  int i = b * 1024 + t;
  if (i < n) { int e = rowptr[i] + off; rowptr[i] = e; cursor[i] = e; }
  if (b == (int)gridDim.x - 1 && t == 1023) rowptr[n] = off + bsum[b];
}

__global__ void fill_kernel(const int* __restrict__ src, const int* __restrict__ dst,
                            int* __restrict__ cursor, int* __restrict__ colsrc, int E, int N) {
  int i = blockIdx.x * blockDim.x + threadIdx.x;
  int tot = E + N;
  if (i >= tot) return;
  int d, s;
  if (i < E) { d = dst[i]; s = src[i]; } else { d = i - E; s = i - E; }
  int pos = atomicAdd(&cursor[d], 1);
  colsrc[pos] = s;
}

// ---------------- fused prep: transposes + f2b(x) + bias concat + cnt/dots zero -------
static __device__ __forceinline__ void do_transpose(
    const float* __restrict__ W, unsigned short* __restrict__ Wt,
    int K, int Ncol, int lbid, float (*t)[33]) {
  int nxb = Ncol >> 5;
  int bx = lbid % nxb, by = lbid / nxb;
  int n0 = bx * 32, k0 = by * 32;
  int tx = threadIdx.x & 31, ty = threadIdx.x >> 5;  // ty 0..7
  #pragma unroll
  for (int i = 0; i < 4; ++i)
    t[ty + i * 8][tx] = W[(size_t)(k0 + ty + i * 8) * Ncol + n0 + tx];
  __syncthreads();
  #pragma unroll
  for (int i = 0; i < 4; ++i)
    Wt[(size_t)(n0 + ty + i * 8) * K + k0 + tx] = f2b(t[tx][ty + i * 8]);
}

// block ranges: [0,16) t0 | [16,272) t1 | [272,528) t2 | [528,1552) t3 |
// [1552,2576) t4 | [2576,2832) t5 | [2832,3088) t6 | [3088,3106) bias |
// [3106, 3106+nbf2b) f2b(x) | rest: zero cnt (N ints) then dots (8N floats)
__global__ __launch_bounds__(256) void prep_all(
    const float* __restrict__ W_in,
    const float* __restrict__ Wl1, const float* __restrict__ Wr1,
    const float* __restrict__ Wl2, const float* __restrict__ Wr2,
    const float* __restrict__ Wl3, const float* __restrict__ Wr3,
    unsigned short* __restrict__ WtIn,
    unsigned short* __restrict__ WtL1, unsigned short* __restrict__ WtR1,
    unsigned short* __restrict__ WtL2, unsigned short* __restrict__ WtR2,
    unsigned short* __restrict__ WtL3, unsigned short* __restrict__ WtR3,
    const float* __restrict__ x, unsigned short* __restrict__ xbf, int nx_elems,
    const float* __restrict__ bl1, const float* __restrict__ br1,
    const float* __restrict__ bl2, const float* __restrict__ br2,
    const float* __restrict__ bl3, const float* __restrict__ br3,
    float* __restrict__ bLR1, float* __restrict__ bLR2, float* __restrict__ bLR3,
    int* __restrict__ cnt, float* __restrict__ dotsAll, int N) {
  __shared__ float t[32][33];
  int bid = blockIdx.x;
  if (bid < 16)        { do_transpose(W_in, WtIn, 64, 256, bid, t); return; }
  if (bid < 272)       { do_transpose(Wl1, WtL1, 256, 1024, bid - 16, t); return; }
  if (bid < 528)       { do_transpose(Wr1, WtR1, 256, 1024, bid - 272, t); return; }
  if (bid < 1552)      { do_transpose(Wl2, WtL2, 1024, 1024, bid - 528, t); return; }
  if (bid < 2576)      { do_transpose(Wr2, WtR2, 1024, 1024, bid - 1552, t); return; }
  if (bid < 2832)      { do_transpose(Wl3, WtL3, 1024, 256, bid - 2576, t); return; }
  if (bid < 3088)      { do_transpose(Wr3, WtR3, 1024, 256, bid - 2832, t); return; }
  if (bid < 3106) {
    int i = (bid - 3088) * 256 + threadIdx.x;   // 0..4607
    if (i < 1024)      bLR1[i] = bl1[i];
    else if (i < 2048) bLR1[i] = br1[i - 1024];
    else if (i < 3072) bLR2[i - 2048] = bl2[i - 2048];
    else if (i < 4096) bLR2[i - 2048] = br2[i - 3072];
    else if (i < 4352) bLR3[i - 4096] = bl3[i - 4096];
    else if (i < 4608) bLR3[i - 4096] = br3[i - 4352];
    return;
  }
  int nbf2b = (nx_elems + 255) / 256;
  if (bid < 3106 + nbf2b) {
    int i = (bid - 3106) * 256 + threadIdx.x;
    if (i < nx_elems) xbf[i] = f2b(x[i]);
    return;
  }
  int i = (bid - 3106 - nbf2b) * 256 + threadIdx.x;
  if (i < N) cnt[i] = 0;
  else if (i < N + 8 * N) dotsAll[i - N] = 0.f;
}

// ---------------- bf16 MFMA GEMM: BK=64, register prefetch, 8-chunk XOR swizzle ------
// Epilogue optionally computes dots[row*4+hd] += sum_col v*0.6*att (xl cols only):
// 4 fma + 4 shuffles per row per thread + 1 atomic per (row, 64-col half). GEMM is
// VALU-idle (19%) so this is nearly free; removes the x*a6 term from the agg loop.
__global__ __launch_bounds__(256) void gemm_mfma(
    const unsigned short* __restrict__ A, const unsigned short* __restrict__ Bt,
    const float* __restrict__ bias, float* __restrict__ Cf, unsigned short* __restrict__ Cb,
    const float* __restrict__ att, float* __restrict__ dots,
    int M, int K, int ldcf, int ldcb, int act) {
  __shared__ __align__(16) unsigned short As[128 * 64];
  __shared__ __align__(16) unsigned short Bs[128 * 64];
  int tid = threadIdx.x;
  int wave = tid >> 6, lane = tid & 63;
  int wm = wave >> 1, wn = wave & 1;
  int quad = lane >> 4, l16 = lane & 15;
  int row0 = blockIdx.y * 128, col0 = blockIdx.x * 128;
  int r0 = tid >> 2, seg0 = tid & 3;
  int f0 = ((r0 & 1) << 2) | ((r0 >> 1) & 3);
  int wsl0 = r0 * 64 + ((seg0 ^ f0) * 8);
  int wsl1 = r0 * 64 + (((seg0 | 4) ^ f0) * 8);
  int wsl2 = wsl0 + 64 * 64;
  int wsl3 = wsl1 + 64 * 64;
  int flane = ((l16 & 1) << 2) | ((l16 >> 1) & 3);

  const unsigned short* gA = A + (size_t)(row0 + r0) * K + seg0 * 8;
  const unsigned short* gB = Bt + (size_t)(col0 + r0) * K + seg0 * 8;
  const size_t rstep = (size_t)64 * K;

  f32x4 acc[4][4];
  #pragma unroll
  for (int i = 0; i < 4; ++i)
    #pragma unroll
    for (int j = 0; j < 4; ++j)
      acc[i][j] = (f32x4){0.f, 0.f, 0.f, 0.f};

  uint4 pa0 = *(const uint4*)(gA);
  uint4 pa1 = *(const uint4*)(gA + 32);
  uint4 pa2 = *(const uint4*)(gA + rstep);
  uint4 pa3 = *(const uint4*)(gA + rstep + 32);
  uint4 pb0 = *(const uint4*)(gB);
  uint4 pb1 = *(const uint4*)(gB + 32);
  uint4 pb2 = *(const uint4*)(gB + rstep);
  uint4 pb3 = *(const uint4*)(gB + rstep + 32);

  for (int k0 = 0; k0 < K; k0 += 64) {
    *(uint4*)&As[wsl0] = pa0;
    *(uint4*)&As[wsl1] = pa1;
    *(uint4*)&As[wsl2] = pa2;
    *(uint4*)&As[wsl3] = pa3;
    *(uint4*)&Bs[wsl0] = pb0;
    *(uint4*)&Bs[wsl1] = pb1;
    *(uint4*)&Bs[wsl2] = pb2;
    *(uint4*)&Bs[wsl3] = pb3;
    __syncthreads();
    int kn = k0 + 64;
    if (kn < K) {
      pa0 = *(const uint4*)(gA + kn);
      pa1 = *(const uint4*)(gA + kn + 32);
      pa2 = *(const uint4*)(gA + kn + rstep);
      pa3 = *(const uint4*)(gA + kn + rstep + 32);
      pb0 = *(const uint4*)(gB + kn);
      pb1 = *(const uint4*)(gB + kn + 32);
      pb2 = *(const uint4*)(gB + kn + rstep);
      pb3 = *(const uint4*)(gB + kn + rstep + 32);
    }
    #pragma unroll
    for (int h = 0; h < 2; ++h) {
      short8 afr[4], bfr[4];
      #pragma unroll
      for (int t = 0; t < 4; ++t) {
        int pcs = (((h << 2) | quad) ^ flane) * 8;
        afr[t] = *(const short8*)&As[(wm * 64 + t * 16 + l16) * 64 + pcs];
        bfr[t] = *(const short8*)&Bs[(wn * 64 + t * 16 + l16) * 64 + pcs];
      }
      #pragma unroll
      for (int mt = 0; mt < 4; ++mt)
        #pragma unroll
        for (int nt = 0; nt < 4; ++nt)
          acc[mt][nt] = __builtin_amdgcn_mfma_f32_16x16x32_bf16(afr[mt], bfr[nt], acc[mt][nt], 0, 0, 0);
    }
    __syncthreads();
  }

  bool dodot = (dots != nullptr) && (col0 < 1024);
  int hd = col0 >> 8;
  float a6e[4] = {0.f, 0.f, 0.f, 0.f};
  if (dodot) {
    #pragma unroll
    for (int nt = 0; nt < 4; ++nt)
      a6e[nt] = 0.6f * att[hd * 256 + (col0 & 255) + wn * 64 + nt * 16 + l16];
  }
  #pragma unroll
  for (int mt = 0; mt < 4; ++mt) {
    #pragma unroll
    for (int r = 0; r < 4; ++r) {
      int row = row0 + wm * 64 + mt * 16 + quad * 4 + r;
      if (row >= M) continue;
      float dp = 0.f;
      #pragma unroll
      for (int nt = 0; nt < 4; ++nt) {
        int col = col0 + wn * 64 + nt * 16 + l16;
        float v = acc[mt][nt][r] + bias[col];
        if (act == 1) v = lrelu(v, NEG);
        if (Cf) Cf[(size_t)row * ldcf + col] = v;
        if (Cb) Cb[(size_t)row * ldcb + col] = f2b(v);
        dp = fmaf(v, a6e[nt], dp);
      }
      if (dodot) {
        dp += __shfl_xor(dp, 1);
        dp += __shfl_xor(dp, 2);
        dp += __shfl_xor(dp, 4);
        dp += __shfl_xor(dp, 8);
        if (l16 == 0) atomicAdd(&dots[row * 4 + hd], dp);
      }
    }
  }
}

// ---------------- GATv2 aggregation, 4 heads: bf16 xlr + precomputed dots ------------
// p_partial(s) = dots[s*4+hd] + sum |x+xr|*0.4a; center = p_partial(d) (self-loop);
// the loop-invariant sum xr*0.6a cancels. Score loop: 4 pk_add + 8 fma per edge.
__global__ __launch_bounds__(256) void gat_agg_h4(
    const unsigned short* __restrict__ xlr, const float* __restrict__ dots,
    const int* __restrict__ rowptr, const int* __restrict__ colsrc,
    const float* __restrict__ att, const float* __restrict__ bias,
    unsigned short* __restrict__ outb, int n) {
  int d = blockIdx.x;
  if (d >= n) return;
  int hd = threadIdx.x >> 6, ln = threadIdx.x & 63;
  int half = ln >> 5, l32 = ln & 31;
  int cbase = hd * 256 + l32 * 8;
  float a4[8];
  f32x2 xr2[4];
  {
    float4 t0 = *(const float4*)(att + cbase);
    float4 t1 = *(const float4*)(att + cbase + 4);
    float a[8] = {t0.x, t0.y, t0.z, t0.w, t1.x, t1.y, t1.z, t1.w};
    #pragma unroll
    for (int c = 0; c < 8; ++c) a4[c] = 0.4f * a[c];
    uint4 r = *(const uint4*)(xlr + ((size_t)d << 11) + 1024 + cbase);
    up2x4(r, xr2);
  }
  // softmax center: psb = dots[d] + sum |xl[d]+xr[d]| * a4
  float psb;
  {
    uint4 r = *(const uint4*)(xlr + ((size_t)d << 11) + cbase);
    f32x2 xs[4];
    up2x4(r, xs);
    float p = 0.f;
    #pragma unroll
    for (int k = 0; k < 4; ++k) {
      f32x2 u = xs[k] + xr2[k];
      p = fmaf(fabsf(u.x), a4[2 * k], p);
      p = fmaf(fabsf(u.y), a4[2 * k + 1], p);
    }
    #pragma unroll
    for (int off = 16; off >= 1; off >>= 1) p += __shfl_xor(p, off);
    psb = p + dots[d * 4 + hd];
  }
  float l = 0.f;
  f32x2 acc2[4];
  #pragma unroll
  for (int k = 0; k < 4; ++k) acc2[k] = (f32x2){0.f, 0.f};
  int beg = rowptr[d], end = rowptr[d + 1];
  for (int j = beg; j < end; j += 4) {
    int j0 = j + half, j1 = j + 2 + half;
    bool v0 = j0 < end, v1 = j1 < end;
    int s0 = colsrc[v0 ? j0 : beg];
    int s1 = colsrc[v1 ? j1 : beg];
    float ds0 = dots[s0 * 4 + hd];
    float ds1 = dots[s1 * 4 + hd];
    uint4 r0 = *(const uint4*)(xlr + ((size_t)s0 << 11) + cbase);
    uint4 r1 = *(const uint4*)(xlr + ((size_t)s1 << 11) + cbase);
    f32x2 x0[4], x1[4];
    up2x4(r0, x0);
    up2x4(r1, x1);
    float p0 = 0.f, p1 = 0.f;
    #pragma unroll
    for (int k = 0; k < 4; ++k) {
      f32x2 u0 = x0[k] + xr2[k];        // v_pk_add_f32
      f32x2 u1 = x1[k] + xr2[k];
      p0 = fmaf(fabsf(u0.x), a4[2 * k], p0);
      p0 = fmaf(fabsf(u0.y), a4[2 * k + 1], p0);
      p1 = fmaf(fabsf(u1.x), a4[2 * k], p1);
      p1 = fmaf(fabsf(u1.y), a4[2 * k + 1], p1);
    }
    #pragma unroll
    for (int off = 16; off >= 1; off >>= 1) {
      p0 += __shfl_xor(p0, off);
      p1 += __shfl_xor(p1, off);
    }
    float w0 = v0 ? __expf(p0 + ds0 - psb) : 0.f;
    float w1 = v1 ? __expf(p1 + ds1 - psb) : 0.f;
    l += w0 + w1;
    f32x2 w02 = {w0, w0}, w12 = {w1, w1};
    #pragma unroll
    for (int k = 0; k < 4; ++k) {
      acc2[k] = w02 * x0[k] + acc2[k];  // v_pk_fma_f32
      acc2[k] = w12 * x1[k] + acc2[k];
    }
  }
  // merge halves (shared center -> plain adds)
  l += __shfl_xor(l, 32);
  float inv = 1.f / l;
  float4 b0 = *(const float4*)(bias + cbase);
  float4 b1 = *(const float4*)(bias + cbase + 4);
  float bb[8] = {b0.x, b0.y, b0.z, b0.w, b1.x, b1.y, b1.z, b1.w};
  unsigned int ou[4];
  #pragma unroll
  for (int k = 0; k < 4; ++k) {
    float sx = acc2[k].x + __shfl_xor(acc2[k].x, 32);
    float sy = acc2[k].y + __shfl_xor(acc2[k].y, 32);
    float vx = sx * inv + bb[2 * k];
    float vy = sy * inv + bb[2 * k + 1];
    vx = vx > 0.f ? vx : expm1f(vx);   // ELU
    vy = vy > 0.f ? vy : expm1f(vy);
    ou[k] = (unsigned int)f2b(vx) | ((unsigned int)f2b(vy) << 16);
  }
  if (half == 0) {
    uint4 o = make_uint4(ou[0], ou[1], ou[2], ou[3]);
    *(uint4*)(outb + (size_t)d * 1024 + cbase) = o;
  }
}

// ---------------- fused layer-3 agg + final logits (664-us baseline, verbatim) -------
__global__ __launch_bounds__(256) void gat_agg_h1_final(
    const unsigned short* __restrict__ xlr,
    const int* __restrict__ rowptr, const int* __restrict__ colsrc,
    const float* __restrict__ att, const float* __restrict__ bias,
    const float* __restrict__ h, const float* __restrict__ Wout,
    const float* __restrict__ bout, float* __restrict__ out, int n) {
  int wv = threadIdx.x >> 6, ln = threadIdx.x & 63;
  int d = blockIdx.x * 4 + wv;
  if (d >= n) return;
  int half = ln >> 5, l32 = ln & 31;
  int c0 = l32 * 8;
  float a6[8], a4[8];
  f32x2 xr2[4];
  {
    float4 t0 = *(const float4*)(att + c0);
    float4 t1 = *(const float4*)(att + c0 + 4);
    float a[8] = {t0.x, t0.y, t0.z, t0.w, t1.x, t1.y, t1.z, t1.w};
    #pragma unroll
    for (int c = 0; c < 8; ++c) { a6[c] = 0.6f * a[c]; a4[c] = 0.4f * a[c]; }
    uint4 r = *(const uint4*)(xlr + ((size_t)d << 9) + 256 + c0);
    up2x4(r, xr2);
  }
  float psp;
  {
    uint4 r = *(const uint4*)(xlr + ((size_t)d << 9) + c0);
    f32x2 xs[4];
    up2x4(r, xs);
    float p = 0.f;
    #pragma unroll
    for (int k = 0; k < 4; ++k) {
      f32x2 u = xs[k] + xr2[k];
      p = fmaf(xs[k].x, a6[2 * k], p);
      p = fmaf(fabsf(u.x), a4[2 * k], p);
      p = fmaf(xs[k].y, a6[2 * k + 1], p);
      p = fmaf(fabsf(u.y), a4[2 * k + 1], p);
    }
    psp = p;
    #pragma unroll
    for (int off = 16; off >= 1; off >>= 1) psp += __shfl_xor(psp, off);
  }
  float l = 0.f;
  f32x2 acc2[4];
  #pragma unroll
  for (int k = 0; k < 4; ++k) acc2[k] = (f32x2){0.f, 0.f};
  int beg = rowptr[d], end = rowptr[d + 1];
  for (int j = beg; j < end; j += 4) {
    int j0 = j + half, j1 = j + 2 + half;
    bool v0 = j0 < end, v1 = j1 < end;
    int s0 = colsrc[v0 ? j0 : beg];
    int s1 = colsrc[v1 ? j1 : beg];
    uint4 r0 = *(const uint4*)(xlr + ((size_t)s0 << 9) + c0);
    uint4 r1 = *(const uint4*)(xlr + ((size_t)s1 << 9) + c0);
    f32x2 x0[4], x1[4];
    up2x4(r0, x0);
    up2x4(r1, x1);
    float p0 = 0.f, p1 = 0.f;
    #pragma unroll
    for (int k = 0; k < 4; ++k) {
      f32x2 u0 = x0[k] + xr2[k];
      f32x2 u1 = x1[k] + xr2[k];
      p0 = fmaf(x0[k].x, a6[2 * k], p0);
      p0 = fmaf(fabsf(u0.x), a4[2 * k], p0);
      p0 = fmaf(x0[k].y, a6[2 * k + 1], p0);
      p0 = fmaf(fabsf(u0.y), a4[2 * k + 1], p0);
      p1 = fmaf(x1[k].x, a6[2 * k], p1);
      p1 = fmaf(fabsf(u1.x), a4[2 * k], p1);
      p1 = fmaf(x1[k].y, a6[2 * k + 1], p1);
      p1 = fmaf(fabsf(u1.y), a4[2 * k + 1], p1);
    }
    #pragma unroll
    for (int off = 16; off >= 1; off >>= 1) {
      p0 += __shfl_xor(p0, off);
      p1 += __shfl_xor(p1, off);
    }
    float w0 = v0 ? __expf(p0 - psp) : 0.f;
    float w1 = v1 ? __expf(p1 - psp) : 0.f;
    l += w0 + w1;
    f32x2 w02 = {w0, w0}, w12 = {w1, w1};
    #pragma unroll
    for (int k = 0; k < 4; ++k) {
      acc2[k] = w02 * x0[k] + acc2[k];
      acc2[k] = w12 * x1[k] + acc2[k];
    }
  }
  l += __shfl_xor(l, 32);
  float inv = 1.f / l;
  float4 b0 = *(const float4*)(bias + c0);
  float4 b1 = *(const float4*)(bias + c0 + 4);
  float bb[8] = {b0.x, b0.y, b0.z, b0.w, b1.x, b1.y, b1.z, b1.w};
  float4 h0 = *(const float4*)(h + (size_t)d * 256 + c0);
  float4 h1v = *(const float4*)(h + (size_t)d * 256 + c0 + 4);
  float hh[8] = {h0.x, h0.y, h0.z, h0.w, h1v.x, h1v.y, h1v.z, h1v.w};
  float4 w0v = *(const float4*)(Wout + c0);
  float4 w1v = *(const float4*)(Wout + c0 + 4);
  float ww[8] = {w0v.x, w0v.y, w0v.z, w0v.w, w1v.x, w1v.y, w1v.z, w1v.w};
  float v = 0.f;
  #pragma unroll
  for (int k = 0; k < 4; ++k) {
    float sx = acc2[k].x + __shfl_xor(acc2[k].x, 32);
    float sy = acc2[k].y + __shfl_xor(acc2[k].y, 32);
    float h3x = sx * inv + bb[2 * k];
    float h3y = sy * inv + bb[2 * k + 1];
    v = fmaf(lrelu(h3x, NEG) + hh[2 * k], ww[2 * k], v);
    v = fmaf(lrelu(h3y, NEG) + hh[2 * k + 1], ww[2 * k + 1], v);
  }
  #pragma unroll
  for (int off = 16; off >= 1; off >>= 1) v += __shfl_xor(v, off);
  if (ln == 0) out[d] = v + bout[0];
}

extern "C" void kernel_launch(void* const* d_in, const int* in_sizes, int n_in,
                              void* d_out, int out_size, void* d_ws, size_t ws_size,
                              hipStream_t stream) {
  const float* x    = (const float*)d_in[0];
  const int*   src  = (const int*)d_in[1];
  const int*   dst  = (const int*)d_in[2];
  const float* W_in = (const float*)d_in[3];
  const float* b_in = (const float*)d_in[4];
  const float* Wl1 = (const float*)d_in[5];  const float* bl1 = (const float*)d_in[6];
  const float* Wr1 = (const float*)d_in[7];  const float* br1 = (const float*)d_in[8];
  const float* att1 = (const float*)d_in[9]; const float* bias1 = (const float*)d_in[10];
  const float* Wl2 = (const float*)d_in[11]; const float* bl2 = (const float*)d_in[12];
  const float* Wr2 = (const float*)d_in[13]; const float* br2 = (const float*)d_in[14];
  const float* att2 = (const float*)d_in[15]; const float* bias2 = (const float*)d_in[16];
  const float* Wl3 = (const float*)d_in[17]; const float* bl3 = (const float*)d_in[18];
  const float* Wr3 = (const float*)d_in[19]; const float* br3 = (const float*)d_in[20];
  const float* att3 = (const float*)d_in[21]; const float* bias3 = (const float*)d_in[22];
  const float* W_out = (const float*)d_in[23]; const float* b_out = (const float*)d_in[24];

  const int N = in_sizes[0] / 64;
  const int E = in_sizes[1];
  const int NP = ((N + 127) / 128) * 128;   // padded rows for GEMM-A buffers
  float* out = (float*)d_out;

  // ---- workspace layout (bf16 xlr; h1/h2 share one buffer; xbf aliases xlr) ----
  char* p = (char*)d_ws;
  float* h    = (float*)p;            p += (size_t)N * 256 * 4;    // fp32 residual
  unsigned short* hbf   = (unsigned short*)p; p += (size_t)NP * 256 * 2;
  unsigned short* h12bf = (unsigned short*)p; p += (size_t)NP * 1024 * 2;
  unsigned short* xlr   = (unsigned short*)p; p += (size_t)N * 2048 * 2;
  unsigned short* WtIn  = (unsigned short*)p; p += (size_t)256 * 64 * 2;
  unsigned short* WtLR1 = (unsigned short*)p; p += (size_t)2048 * 256 * 2;
  unsigned short* WtLR2 = (unsigned short*)p; p += (size_t)2048 * 1024 * 2;
  unsigned short* WtLR3 = (unsigned short*)p; p += (size_t)512 * 1024 * 2;
  float* bLR1 = (float*)p;            p += (size_t)2048 * 4;
  float* bLR2 = (float*)p;            p += (size_t)2048 * 4;
  float* bLR3 = (float*)p;            p += (size_t)512 * 4;
  float* dots1 = (float*)p;           p += (size_t)N * 4 * 4;      // per-(node,head) x.a6
  float* dots2 = (float*)p;           p += (size_t)N * 4 * 4;
  int* bsum   = (int*)p;              p += (size_t)64 * 4;
  int* cnt    = (int*)p;              p += (size_t)N * 4;
  int* cursor = (int*)p;              p += (size_t)N * 4;
  int* rowptr = (int*)p;              p += (size_t)(N + 1) * 4;
  int* colsrc = (int*)p;
  unsigned short* xbf = xlr;          // alias: dead before first xlr write

  const int tot = E + N;
  dim3 blk(256);

  // fused prep: transposes + f2b(x) + bias concat + cnt/dots zero in one dispatch
  int nbf2b = (N * 64 + 255) / 256;
  int nz = (9 * N + 255) / 256;       // N ints (cnt) + 8N floats (dots1|dots2)
  prep_all<<<3106 + nbf2b + nz, blk, 0, stream>>>(
      W_in, Wl1, Wr1, Wl2, Wr2, Wl3, Wr3,
      WtIn, WtLR1, WtLR1 + (size_t)1024 * 256,
      WtLR2, WtLR2 + (size_t)1024 * 1024,
      WtLR3, WtLR3 + (size_t)256 * 1024,
      x, xbf, N * 64,
      bl1, br1, bl2, br2, bl3, br3, bLR1, bLR2, bLR3,
      cnt, dots1, N);

  // CSR build (by dst, self loops appended); two-phase parallel scan
  int nsb = (N + 1023) / 1024;
  hist_kernel<<<(tot + 255) / 256, blk, 0, stream>>>(dst, cnt, E, N);
  scan1_kernel<<<nsb, 1024, 0, stream>>>(cnt, rowptr, bsum, N);
  scan2_kernel<<<nsb, 1024, 0, stream>>>(rowptr, cursor, bsum, N);
  fill_kernel<<<(tot + 255) / 256, blk, 0, stream>>>(src, dst, cursor, colsrc, E, N);

  int gy = NP / 128;
  int gagg4 = N;
  int gagg1 = (N + 3) / 4;

  // h = leaky(x @ W_in + b_in): fp32 h + bf16 hbf   [K=64]
  gemm_mfma<<<dim3(2, gy), blk, 0, stream>>>(xbf, WtIn, b_in, h, hbf,
                                             nullptr, nullptr, N, 64, 256, 256, 1);

  // layer 1: K=256, fused L|R -> xlr [N,2048] bf16; dots1 fused into epilogue
  gemm_mfma<<<dim3(16, gy), blk, 0, stream>>>(hbf, WtLR1, bLR1, nullptr, xlr,
                                              att1, dots1, N, 256, 0, 2048, 0);
  gat_agg_h4<<<gagg4, blk, 0, stream>>>(xlr, dots1, rowptr, colsrc, att1, bias1, h12bf, N);

  // layer 2: K=1024, fused L|R -> xlr [N,2048] bf16; dots2 fused into epilogue
  gemm_mfma<<<dim3(16, gy), blk, 0, stream>>>(h12bf, WtLR2, bLR2, nullptr, xlr,
                                              att2, dots2, N, 1024, 0, 2048, 0);
  gat_agg_h4<<<gagg4, blk, 0, stream>>>(xlr, dots2, rowptr, colsrc, att2, bias2, h12bf, N);

  // layer 3: K=1024, fused L|R -> xlr [N,512] bf16; agg + residual + logits fused
  gemm_mfma<<<dim3(4, gy), blk, 0, stream>>>(h12bf, WtLR3, bLR3, nullptr, xlr,
                                             nullptr, nullptr, N, 1024, 0, 512, 0);
  gat_agg_h1_final<<<gagg1, blk, 0, stream>>>(xlr, rowptr, colsrc, att3, bias3,
                                              h, W_out, b_out, out, N);
}

// Round 16
// 659.343 us; speedup vs baseline: 1.0750x; 1.0750x over previous
//
#include <hip/hip_runtime.h>
#include <math.h>

#define NEG_ATT 0.2f
#define NEG 0.01f

typedef __attribute__((ext_vector_type(8))) short short8;
typedef __attribute__((ext_vector_type(4))) float f32x4;
typedef __attribute__((ext_vector_type(2))) float f32x2;

static __device__ __forceinline__ float lrelu(float x, float s) { return x > 0.f ? x : s * x; }
static __device__ __forceinline__ unsigned short f2b(float f) {
  union { float f; unsigned int i; } v; v.f = f;
  unsigned int r = (v.i + 0x7fffu + ((v.i >> 16) & 1u)) >> 16;
  return (unsigned short)r;
}
// unpack uint4 (8 bf16) -> 4 float2 pairs
static __device__ __forceinline__ void up2x4(uint4 r, f32x2* v) {
  union { unsigned int i; float f; } t;
  t.i = r.x << 16;          v[0].x = t.f;
  t.i = r.x & 0xffff0000u;  v[0].y = t.f;
  t.i = r.y << 16;          v[1].x = t.f;
  t.i = r.y & 0xffff0000u;  v[1].y = t.f;
  t.i = r.z << 16;          v[2].x = t.f;
  t.i = r.z & 0xffff0000u;  v[2].y = t.f;
  t.i = r.w << 16;          v[3].x = t.f;
  t.i = r.w & 0xffff0000u;  v[3].y = t.f;
}

// ---------------- CSR build ----------------
__global__ void hist_kernel(const int* __restrict__ dst, int* __restrict__ cnt, int E, int N) {
  int i = blockIdx.x * blockDim.x + threadIdx.x;
  int tot = E + N;
  if (i >= tot) return;
  int d = (i < E) ? dst[i] : (i - E);
  atomicAdd(&cnt[d], 1);
}

// two-phase parallel exclusive scan over n counts
__global__ void scan1_kernel(const int* __restrict__ cnt, int* __restrict__ rowptr,
                             int* __restrict__ bsum, int n) {
  __shared__ int wsum[16];
  int t = threadIdx.x, lane = t & 63, wv = t >> 6;
  int i = blockIdx.x * 1024 + t;
  int orig = (i < n) ? cnt[i] : 0;
  int v = orig;
  #pragma unroll
  for (int off = 1; off < 64; off <<= 1) {
    int u = __shfl_up(v, off);
    if (lane >= off) v += u;
  }
  if (lane == 63) wsum[wv] = v;
  __syncthreads();
  if (t < 16) {
    int s = wsum[t];
    #pragma unroll
    for (int off = 1; off < 16; off <<= 1) {
      int u = __shfl_up(s, off);
      if (t >= off) s += u;
    }
    wsum[t] = s;
  }
  __syncthreads();
  int waveoff = (wv > 0) ? wsum[wv - 1] : 0;
  if (i < n) rowptr[i] = waveoff + v - orig;   // exclusive within block
  if (t == 1023) bsum[blockIdx.x] = wsum[15];
}

__global__ void scan2_kernel(int* __restrict__ rowptr, int* __restrict__ cursor,
                             const int* __restrict__ bsum, int n) {
  int t = threadIdx.x, b = blockIdx.x;
  int off = 0;
  for (int k = 0; k < b; ++k) off += bsum[k];
  int i = b * 1024 + t;
  if (i < n) { int e = rowptr[i] + off; rowptr[i] = e; cursor[i] = e; }
  if (b == (int)gridDim.x - 1 && t == 1023) rowptr[n] = off + bsum[b];
}

__global__ void fill_kernel(const int* __restrict__ src, const int* __restrict__ dst,
                            int* __restrict__ cursor, int* __restrict__ colsrc, int E, int N) {
  int i = blockIdx.x * blockDim.x + threadIdx.x;
  int tot = E + N;
  if (i >= tot) return;
  int d, s;
  if (i < E) { d = dst[i]; s = src[i]; } else { d = i - E; s = i - E; }
  int pos = atomicAdd(&cursor[d], 1);
  colsrc[pos] = s;
}

// ---------------- fused prep: transposes + f2b(x) + bias concat + cnt zero ----------
static __device__ __forceinline__ void do_transpose(
    const float* __restrict__ W, unsigned short* __restrict__ Wt,
    int K, int Ncol, int lbid, float (*t)[33]) {
  int nxb = Ncol >> 5;
  int bx = lbid % nxb, by = lbid / nxb;
  int n0 = bx * 32, k0 = by * 32;
  int tx = threadIdx.x & 31, ty = threadIdx.x >> 5;  // ty 0..7
  #pragma unroll
  for (int i = 0; i < 4; ++i)
    t[ty + i * 8][tx] = W[(size_t)(k0 + ty + i * 8) * Ncol + n0 + tx];
  __syncthreads();
  #pragma unroll
  for (int i = 0; i < 4; ++i)
    Wt[(size_t)(n0 + ty + i * 8) * K + k0 + tx] = f2b(t[tx][ty + i * 8]);
}

// block ranges: [0,16) t0 | [16,272) t1 | [272,528) t2 | [528,1552) t3 |
// [1552,2576) t4 | [2576,2832) t5 | [2832,3088) t6 | [3088,3106) bias |
// [3106, 3106+nbf2b) f2b(x) | rest: zero cnt (N ints)
__global__ __launch_bounds__(256) void prep_all(
    const float* __restrict__ W_in,
    const float* __restrict__ Wl1, const float* __restrict__ Wr1,
    const float* __restrict__ Wl2, const float* __restrict__ Wr2,
    const float* __restrict__ Wl3, const float* __restrict__ Wr3,
    unsigned short* __restrict__ WtIn,
    unsigned short* __restrict__ WtL1, unsigned short* __restrict__ WtR1,
    unsigned short* __restrict__ WtL2, unsigned short* __restrict__ WtR2,
    unsigned short* __restrict__ WtL3, unsigned short* __restrict__ WtR3,
    const float* __restrict__ x, unsigned short* __restrict__ xbf, int nx_elems,
    const float* __restrict__ bl1, const float* __restrict__ br1,
    const float* __restrict__ bl2, const float* __restrict__ br2,
    const float* __restrict__ bl3, const float* __restrict__ br3,
    float* __restrict__ bLR1, float* __restrict__ bLR2, float* __restrict__ bLR3,
    int* __restrict__ cnt, int N) {
  __shared__ float t[32][33];
  int bid = blockIdx.x;
  if (bid < 16)        { do_transpose(W_in, WtIn, 64, 256, bid, t); return; }
  if (bid < 272)       { do_transpose(Wl1, WtL1, 256, 1024, bid - 16, t); return; }
  if (bid < 528)       { do_transpose(Wr1, WtR1, 256, 1024, bid - 272, t); return; }
  if (bid < 1552)      { do_transpose(Wl2, WtL2, 1024, 1024, bid - 528, t); return; }
  if (bid < 2576)      { do_transpose(Wr2, WtR2, 1024, 1024, bid - 1552, t); return; }
  if (bid < 2832)      { do_transpose(Wl3, WtL3, 1024, 256, bid - 2576, t); return; }
  if (bid < 3088)      { do_transpose(Wr3, WtR3, 1024, 256, bid - 2832, t); return; }
  if (bid < 3106) {
    int i = (bid - 3088) * 256 + threadIdx.x;   // 0..4607
    if (i < 1024)      bLR1[i] = bl1[i];
    else if (i < 2048) bLR1[i] = br1[i - 1024];
    else if (i < 3072) bLR2[i - 2048] = bl2[i - 2048];
    else if (i < 4096) bLR2[i - 2048] = br2[i - 3072];
    else if (i < 4352) bLR3[i - 4096] = bl3[i - 4096];
    else if (i < 4608) bLR3[i - 4096] = br3[i - 4352];
    return;
  }
  int nbf2b = (nx_elems + 255) / 256;
  if (bid < 3106 + nbf2b) {
    int i = (bid - 3106) * 256 + threadIdx.x;
    if (i < nx_elems) xbf[i] = f2b(x[i]);
    return;
  }
  int i = (bid - 3106 - nbf2b) * 256 + threadIdx.x;
  if (i < N) cnt[i] = 0;
}

// ---------------- bf16 MFMA GEMM: BK=64, register prefetch, 8-chunk XOR swizzle ------
// (the 652-us round-14 GEMM, verbatim)
__global__ __launch_bounds__(256) void gemm_mfma(
    const unsigned short* __restrict__ A, const unsigned short* __restrict__ Bt,
    const float* __restrict__ bias, float* __restrict__ Cf, unsigned short* __restrict__ Cb,
    int M, int K, int ldcf, int ldcb, int act) {
  __shared__ __align__(16) unsigned short As[128 * 64];
  __shared__ __align__(16) unsigned short Bs[128 * 64];
  int tid = threadIdx.x;
  int wave = tid >> 6, lane = tid & 63;
  int wm = wave >> 1, wn = wave & 1;
  int quad = lane >> 4, l16 = lane & 15;
  int row0 = blockIdx.y * 128, col0 = blockIdx.x * 128;
  int r0 = tid >> 2, seg0 = tid & 3;
  int f0 = ((r0 & 1) << 2) | ((r0 >> 1) & 3);
  int wsl0 = r0 * 64 + ((seg0 ^ f0) * 8);
  int wsl1 = r0 * 64 + (((seg0 | 4) ^ f0) * 8);
  int wsl2 = wsl0 + 64 * 64;
  int wsl3 = wsl1 + 64 * 64;
  int flane = ((l16 & 1) << 2) | ((l16 >> 1) & 3);

  const unsigned short* gA = A + (size_t)(row0 + r0) * K + seg0 * 8;
  const unsigned short* gB = Bt + (size_t)(col0 + r0) * K + seg0 * 8;
  const size_t rstep = (size_t)64 * K;

  f32x4 acc[4][4];
  #pragma unroll
  for (int i = 0; i < 4; ++i)
    #pragma unroll
    for (int j = 0; j < 4; ++j)
      acc[i][j] = (f32x4){0.f, 0.f, 0.f, 0.f};

  uint4 pa0 = *(const uint4*)(gA);
  uint4 pa1 = *(const uint4*)(gA + 32);
  uint4 pa2 = *(const uint4*)(gA + rstep);
  uint4 pa3 = *(const uint4*)(gA + rstep + 32);
  uint4 pb0 = *(const uint4*)(gB);
  uint4 pb1 = *(const uint4*)(gB + 32);
  uint4 pb2 = *(const uint4*)(gB + rstep);
  uint4 pb3 = *(const uint4*)(gB + rstep + 32);

  for (int k0 = 0; k0 < K; k0 += 64) {
    *(uint4*)&As[wsl0] = pa0;
    *(uint4*)&As[wsl1] = pa1;
    *(uint4*)&As[wsl2] = pa2;
    *(uint4*)&As[wsl3] = pa3;
    *(uint4*)&Bs[wsl0] = pb0;
    *(uint4*)&Bs[wsl1] = pb1;
    *(uint4*)&Bs[wsl2] = pb2;
    *(uint4*)&Bs[wsl3] = pb3;
    __syncthreads();
    int kn = k0 + 64;
    if (kn < K) {
      pa0 = *(const uint4*)(gA + kn);
      pa1 = *(const uint4*)(gA + kn + 32);
      pa2 = *(const uint4*)(gA + kn + rstep);
      pa3 = *(const uint4*)(gA + kn + rstep + 32);
      pb0 = *(const uint4*)(gB + kn);
      pb1 = *(const uint4*)(gB + kn + 32);
      pb2 = *(const uint4*)(gB + kn + rstep);
      pb3 = *(const uint4*)(gB + kn + rstep + 32);
    }
    #pragma unroll
    for (int h = 0; h < 2; ++h) {
      short8 afr[4], bfr[4];
      #pragma unroll
      for (int t = 0; t < 4; ++t) {
        int pcs = (((h << 2) | quad) ^ flane) * 8;
        afr[t] = *(const short8*)&As[(wm * 64 + t * 16 + l16) * 64 + pcs];
        bfr[t] = *(const short8*)&Bs[(wn * 64 + t * 16 + l16) * 64 + pcs];
      }
      #pragma unroll
      for (int mt = 0; mt < 4; ++mt)
        #pragma unroll
        for (int nt = 0; nt < 4; ++nt)
          acc[mt][nt] = __builtin_amdgcn_mfma_f32_16x16x32_bf16(afr[mt], bfr[nt], acc[mt][nt], 0, 0, 0);
    }
    __syncthreads();
  }

  #pragma unroll
  for (int mt = 0; mt < 4; ++mt) {
    #pragma unroll
    for (int r = 0; r < 4; ++r) {
      int row = row0 + wm * 64 + mt * 16 + quad * 4 + r;
      if (row >= M) continue;
      #pragma unroll
      for (int nt = 0; nt < 4; ++nt) {
        int col = col0 + wn * 64 + nt * 16 + l16;
        float v = acc[mt][nt][r] + bias[col];
        if (act == 1) v = lrelu(v, NEG);
        if (Cf) Cf[(size_t)row * ldcf + col] = v;
        if (Cb) Cb[(size_t)row * ldcb + col] = f2b(v);
      }
    }
  }
}

// ---------------- GATv2 aggregation, 4 heads (round-14 form + 32-bit addressing) -----
// leaky02(u) = 0.6u + 0.4|u|; loop-invariant xr*0.6a cancels vs the self-center.
__global__ __launch_bounds__(256) void gat_agg_h4(
    const unsigned short* __restrict__ xlr,
    const int* __restrict__ rowptr, const int* __restrict__ colsrc,
    const float* __restrict__ att, const float* __restrict__ bias,
    unsigned short* __restrict__ outb, int n) {
  int d = blockIdx.x;
  if (d >= n) return;
  int hd = threadIdx.x >> 6, ln = threadIdx.x & 63;
  int half = ln >> 5, l32 = ln & 31;
  unsigned cbase = (unsigned)(hd * 256 + l32 * 8);
  float a6[8], a4[8];
  f32x2 xr2[4];
  {
    float4 t0 = *(const float4*)(att + cbase);
    float4 t1 = *(const float4*)(att + cbase + 4);
    float a[8] = {t0.x, t0.y, t0.z, t0.w, t1.x, t1.y, t1.z, t1.w};
    #pragma unroll
    for (int c = 0; c < 8; ++c) { a6[c] = 0.6f * a[c]; a4[c] = 0.4f * a[c]; }
    uint4 r = *(const uint4*)(xlr + (((unsigned)d << 11) + 1024u + cbase));
    up2x4(r, xr2);
  }
  // self-loop partial score (shared softmax center; xr*a6 term cancels)
  float psp;
  {
    uint4 r = *(const uint4*)(xlr + (((unsigned)d << 11) + cbase));
    f32x2 xs[4];
    up2x4(r, xs);
    f32x2 p2 = {0.f, 0.f};
    #pragma unroll
    for (int k = 0; k < 4; ++k) {
      f32x2 u = xs[k] + xr2[k];
      p2.x = fmaf(xs[k].x, a6[2 * k], p2.x);
      p2.x = fmaf(fabsf(u.x), a4[2 * k], p2.x);
      p2.y = fmaf(xs[k].y, a6[2 * k + 1], p2.y);
      p2.y = fmaf(fabsf(u.y), a4[2 * k + 1], p2.y);
    }
    psp = p2.x + p2.y;
    #pragma unroll
    for (int off = 16; off >= 1; off >>= 1) psp += __shfl_xor(psp, off);
  }
  float l = 0.f;
  f32x2 acc2[4];
  #pragma unroll
  for (int k = 0; k < 4; ++k) acc2[k] = (f32x2){0.f, 0.f};
  int beg = rowptr[d], end = rowptr[d + 1];
  for (int j = beg; j < end; j += 4) {
    int j0 = j + half, j1 = j + 2 + half;
    bool v0 = j0 < end, v1 = j1 < end;
    unsigned o0 = ((unsigned)colsrc[v0 ? j0 : beg] << 11) + cbase;
    unsigned o1 = ((unsigned)colsrc[v1 ? j1 : beg] << 11) + cbase;
    uint4 r0 = *(const uint4*)(xlr + o0);
    uint4 r1 = *(const uint4*)(xlr + o1);
    f32x2 x0[4], x1[4];
    up2x4(r0, x0);
    up2x4(r1, x1);
    float p0 = 0.f, p1 = 0.f;
    #pragma unroll
    for (int k = 0; k < 4; ++k) {
      f32x2 u0 = x0[k] + xr2[k];        // v_pk_add_f32
      f32x2 u1 = x1[k] + xr2[k];
      p0 = fmaf(x0[k].x, a6[2 * k], p0);
      p0 = fmaf(fabsf(u0.x), a4[2 * k], p0);
      p0 = fmaf(x0[k].y, a6[2 * k + 1], p0);
      p0 = fmaf(fabsf(u0.y), a4[2 * k + 1], p0);
      p1 = fmaf(x1[k].x, a6[2 * k], p1);
      p1 = fmaf(fabsf(u1.x), a4[2 * k], p1);
      p1 = fmaf(x1[k].y, a6[2 * k + 1], p1);
      p1 = fmaf(fabsf(u1.y), a4[2 * k + 1], p1);
    }
    #pragma unroll
    for (int off = 16; off >= 1; off >>= 1) {
      p0 += __shfl_xor(p0, off);
      p1 += __shfl_xor(p1, off);
    }
    float w0 = v0 ? __expf(p0 - psp) : 0.f;
    float w1 = v1 ? __expf(p1 - psp) : 0.f;
    l += w0 + w1;
    f32x2 w02 = {w0, w0}, w12 = {w1, w1};
    #pragma unroll
    for (int k = 0; k < 4; ++k) {
      acc2[k] = w02 * x0[k] + acc2[k];  // v_pk_fma_f32
      acc2[k] = w12 * x1[k] + acc2[k];
    }
  }
  // merge halves (shared center -> plain adds)
  l += __shfl_xor(l, 32);
  float inv = 1.f / l;
  float4 b0 = *(const float4*)(bias + cbase);
  float4 b1 = *(const float4*)(bias + cbase + 4);
  float bb[8] = {b0.x, b0.y, b0.z, b0.w, b1.x, b1.y, b1.z, b1.w};
  unsigned int ou[4];
  #pragma unroll
  for (int k = 0; k < 4; ++k) {
    float sx = acc2[k].x + __shfl_xor(acc2[k].x, 32);
    float sy = acc2[k].y + __shfl_xor(acc2[k].y, 32);
    float vx = sx * inv + bb[2 * k];
    float vy = sy * inv + bb[2 * k + 1];
    vx = vx > 0.f ? vx : expm1f(vx);   // ELU
    vy = vy > 0.f ? vy : expm1f(vy);
    ou[k] = (unsigned int)f2b(vx) | ((unsigned int)f2b(vy) << 16);
  }
  if (half == 0) {
    uint4 o = make_uint4(ou[0], ou[1], ou[2], ou[3]);
    *(uint4*)(outb + (((unsigned)d << 10) + cbase)) = o;
  }
}

// ---------------- fused layer-3 agg + final logits (round-14 + 32-bit addressing) ----
__global__ __launch_bounds__(256) void gat_agg_h1_final(
    const unsigned short* __restrict__ xlr,
    const int* __restrict__ rowptr, const int* __restrict__ colsrc,
    const float* __restrict__ att, const float* __restrict__ bias,
    const float* __restrict__ h, const float* __restrict__ Wout,
    const float* __restrict__ bout, float* __restrict__ out, int n) {
  int wv = threadIdx.x >> 6, ln = threadIdx.x & 63;
  int d = blockIdx.x * 4 + wv;
  if (d >= n) return;
  int half = ln >> 5, l32 = ln & 31;
  unsigned c0 = (unsigned)(l32 * 8);
  float a6[8], a4[8];
  f32x2 xr2[4];
  {
    float4 t0 = *(const float4*)(att + c0);
    float4 t1 = *(const float4*)(att + c0 + 4);
    float a[8] = {t0.x, t0.y, t0.z, t0.w, t1.x, t1.y, t1.z, t1.w};
    #pragma unroll
    for (int c = 0; c < 8; ++c) { a6[c] = 0.6f * a[c]; a4[c] = 0.4f * a[c]; }
    uint4 r = *(const uint4*)(xlr + (((unsigned)d << 9) + 256u + c0));
    up2x4(r, xr2);
  }
  float psp;
  {
    uint4 r = *(const uint4*)(xlr + (((unsigned)d << 9) + c0));
    f32x2 xs[4];
    up2x4(r, xs);
    float p = 0.f;
    #pragma unroll
    for (int k = 0; k < 4; ++k) {
      f32x2 u = xs[k] + xr2[k];
      p = fmaf(xs[k].x, a6[2 * k], p);
      p = fmaf(fabsf(u.x), a4[2 * k], p);
      p = fmaf(xs[k].y, a6[2 * k + 1], p);
      p = fmaf(fabsf(u.y), a4[2 * k + 1], p);
    }
    psp = p;
    #pragma unroll
    for (int off = 16; off >= 1; off >>= 1) psp += __shfl_xor(psp, off);
  }
  float l = 0.f;
  f32x2 acc2[4];
  #pragma unroll
  for (int k = 0; k < 4; ++k) acc2[k] = (f32x2){0.f, 0.f};
  int beg = rowptr[d], end = rowptr[d + 1];
  for (int j = beg; j < end; j += 4) {
    int j0 = j + half, j1 = j + 2 + half;
    bool v0 = j0 < end, v1 = j1 < end;
    unsigned o0 = ((unsigned)colsrc[v0 ? j0 : beg] << 9) + c0;
    unsigned o1 = ((unsigned)colsrc[v1 ? j1 : beg] << 9) + c0;
    uint4 r0 = *(const uint4*)(xlr + o0);
    uint4 r1 = *(const uint4*)(xlr + o1);
    f32x2 x0[4], x1[4];
    up2x4(r0, x0);
    up2x4(r1, x1);
    float p0 = 0.f, p1 = 0.f;
    #pragma unroll
    for (int k = 0; k < 4; ++k) {
      f32x2 u0 = x0[k] + xr2[k];
      f32x2 u1 = x1[k] + xr2[k];
      p0 = fmaf(x0[k].x, a6[2 * k], p0);
      p0 = fmaf(fabsf(u0.x), a4[2 * k], p0);
      p0 = fmaf(x0[k].y, a6[2 * k + 1], p0);
      p0 = fmaf(fabsf(u0.y), a4[2 * k + 1], p0);
      p1 = fmaf(x1[k].x, a6[2 * k], p1);
      p1 = fmaf(fabsf(u1.x), a4[2 * k], p1);
      p1 = fmaf(x1[k].y, a6[2 * k + 1], p1);
      p1 = fmaf(fabsf(u1.y), a4[2 * k + 1], p1);
    }
    #pragma unroll
    for (int off = 16; off >= 1; off >>= 1) {
      p0 += __shfl_xor(p0, off);
      p1 += __shfl_xor(p1, off);
    }
    float w0 = v0 ? __expf(p0 - psp) : 0.f;
    float w1 = v1 ? __expf(p1 - psp) : 0.f;
    l += w0 + w1;
    f32x2 w02 = {w0, w0}, w12 = {w1, w1};
    #pragma unroll
    for (int k = 0; k < 4; ++k) {
      acc2[k] = w02 * x0[k] + acc2[k];
      acc2[k] = w12 * x1[k] + acc2[k];
    }
  }
  l += __shfl_xor(l, 32);
  float inv = 1.f / l;
  float4 b0 = *(const float4*)(bias + c0);
  float4 b1 = *(const float4*)(bias + c0 + 4);
  float bb[8] = {b0.x, b0.y, b0.z, b0.w, b1.x, b1.y, b1.z, b1.w};
  float4 h0 = *(const float4*)(h + (((unsigned)d << 8) + c0));
  float4 h1v = *(const float4*)(h + (((unsigned)d << 8) + c0 + 4));
  float hh[8] = {h0.x, h0.y, h0.z, h0.w, h1v.x, h1v.y, h1v.z, h1v.w};
  float4 w0v = *(const float4*)(Wout + c0);
  float4 w1v = *(const float4*)(Wout + c0 + 4);
  float ww[8] = {w0v.x, w0v.y, w0v.z, w0v.w, w1v.x, w1v.y, w1v.z, w1v.w};
  float v = 0.f;
  #pragma unroll
  for (int k = 0; k < 4; ++k) {
    float sx = acc2[k].x + __shfl_xor(acc2[k].x, 32);
    float sy = acc2[k].y + __shfl_xor(acc2[k].y, 32);
    float h3x = sx * inv + bb[2 * k];
    float h3y = sy * inv + bb[2 * k + 1];
    v = fmaf(lrelu(h3x, NEG) + hh[2 * k], ww[2 * k], v);
    v = fmaf(lrelu(h3y, NEG) + hh[2 * k + 1], ww[2 * k + 1], v);
  }
  #pragma unroll
  for (int off = 16; off >= 1; off >>= 1) v += __shfl_xor(v, off);
  if (ln == 0) out[d] = v + bout[0];
}

extern "C" void kernel_launch(void* const* d_in, const int* in_sizes, int n_in,
                              void* d_out, int out_size, void* d_ws, size_t ws_size,
                              hipStream_t stream) {
  const float* x    = (const float*)d_in[0];
  const int*   src  = (const int*)d_in[1];
  const int*   dst  = (const int*)d_in[2];
  const float* W_in = (const float*)d_in[3];
  const float* b_in = (const float*)d_in[4];
  const float* Wl1 = (const float*)d_in[5];  const float* bl1 = (const float*)d_in[6];
  const float* Wr1 = (const float*)d_in[7];  const float* br1 = (const float*)d_in[8];
  const float* att1 = (const float*)d_in[9]; const float* bias1 = (const float*)d_in[10];
  const float* Wl2 = (const float*)d_in[11]; const float* bl2 = (const float*)d_in[12];
  const float* Wr2 = (const float*)d_in[13]; const float* br2 = (const float*)d_in[14];
  const float* att2 = (const float*)d_in[15]; const float* bias2 = (const float*)d_in[16];
  const float* Wl3 = (const float*)d_in[17]; const float* bl3 = (const float*)d_in[18];
  const float* Wr3 = (const float*)d_in[19]; const float* br3 = (const float*)d_in[20];
  const float* att3 = (const float*)d_in[21]; const float* bias3 = (const float*)d_in[22];
  const float* W_out = (const float*)d_in[23]; const float* b_out = (const float*)d_in[24];

  const int N = in_sizes[0] / 64;
  const int E = in_sizes[1];
  const int NP = ((N + 127) / 128) * 128;   // padded rows for GEMM-A buffers
  float* out = (float*)d_out;

  // ---- workspace layout (bf16 xlr; h1/h2 share one buffer; xbf aliases xlr) ----
  char* p = (char*)d_ws;
  float* h    = (float*)p;            p += (size_t)N * 256 * 4;    // fp32 residual
  unsigned short* hbf   = (unsigned short*)p; p += (size_t)NP * 256 * 2;
  unsigned short* h12bf = (unsigned short*)p; p += (size_t)NP * 1024 * 2;
  unsigned short* xlr   = (unsigned short*)p; p += (size_t)N * 2048 * 2;
  unsigned short* WtIn  = (unsigned short*)p; p += (size_t)256 * 64 * 2;
  unsigned short* WtLR1 = (unsigned short*)p; p += (size_t)2048 * 256 * 2;
  unsigned short* WtLR2 = (unsigned short*)p; p += (size_t)2048 * 1024 * 2;
  unsigned short* WtLR3 = (unsigned short*)p; p += (size_t)512 * 1024 * 2;
  float* bLR1 = (float*)p;            p += (size_t)2048 * 4;
  float* bLR2 = (float*)p;            p += (size_t)2048 * 4;
  float* bLR3 = (float*)p;            p += (size_t)512 * 4;
  int* bsum   = (int*)p;              p += (size_t)64 * 4;
  int* cnt    = (int*)p;              p += (size_t)N * 4;
  int* cursor = (int*)p;              p += (size_t)N * 4;
  int* rowptr = (int*)p;              p += (size_t)(N + 1) * 4;
  int* colsrc = (int*)p;
  unsigned short* xbf = xlr;          // alias: dead before first xlr write

  const int tot = E + N;
  dim3 blk(256);

  // fused prep: all transposes + f2b(x) + bias concat + cnt zero in one dispatch
  int nbf2b = (N * 64 + 255) / 256;
  int nz = (N + 255) / 256;
  prep_all<<<3106 + nbf2b + nz, blk, 0, stream>>>(
      W_in, Wl1, Wr1, Wl2, Wr2, Wl3, Wr3,
      WtIn, WtLR1, WtLR1 + (size_t)1024 * 256,
      WtLR2, WtLR2 + (size_t)1024 * 1024,
      WtLR3, WtLR3 + (size_t)256 * 1024,
      x, xbf, N * 64,
      bl1, br1, bl2, br2, bl3, br3, bLR1, bLR2, bLR3,
      cnt, N);

  // CSR build (by dst, self loops appended); two-phase parallel scan
  int nsb = (N + 1023) / 1024;
  hist_kernel<<<(tot + 255) / 256, blk, 0, stream>>>(dst, cnt, E, N);
  scan1_kernel<<<nsb, 1024, 0, stream>>>(cnt, rowptr, bsum, N);
  scan2_kernel<<<nsb, 1024, 0, stream>>>(rowptr, cursor, bsum, N);
  fill_kernel<<<(tot + 255) / 256, blk, 0, stream>>>(src, dst, cursor, colsrc, E, N);

  int gy = NP / 128;
  int gagg4 = N;
  int gagg1 = (N + 3) / 4;

  // h = leaky(x @ W_in + b_in): fp32 h + bf16 hbf   [K=64]
  gemm_mfma<<<dim3(2, gy), blk, 0, stream>>>(xbf, WtIn, b_in, h, hbf, N, 64, 256, 256, 1);

  // layer 1: K=256, fused L|R -> xlr [N,2048] bf16
  gemm_mfma<<<dim3(16, gy), blk, 0, stream>>>(hbf, WtLR1, bLR1, nullptr, xlr, N, 256, 0, 2048, 0);
  gat_agg_h4<<<gagg4, blk, 0, stream>>>(xlr, rowptr, colsrc, att1, bias1, h12bf, N);

  // layer 2: K=1024, fused L|R -> xlr [N,2048] bf16
  gemm_mfma<<<dim3(16, gy), blk, 0, stream>>>(h12bf, WtLR2, bLR2, nullptr, xlr, N, 1024, 0, 2048, 0);
  gat_agg_h4<<<gagg4, blk, 0, stream>>>(xlr, rowptr, colsrc, att2, bias2, h12bf, N);

  // layer 3: K=1024, fused L|R -> xlr [N,512] bf16; agg + residual + logits fused
  gemm_mfma<<<dim3(4, gy), blk, 0, stream>>>(h12bf, WtLR3, bLR3, nullptr, xlr, N, 1024, 0, 512, 0);
  gat_agg_h1_final<<<gagg1, blk, 0, stream>>>(xlr, rowptr, colsrc, att3, bias3,
                                              h, W_out, b_out, out, N);
}

// Round 17
// 651.576 us; speedup vs baseline: 1.0878x; 1.0119x over previous
//
#include <hip/hip_runtime.h>
#include <math.h>

#define NEG_ATT 0.2f
#define NEG 0.01f

typedef __attribute__((ext_vector_type(8))) short short8;
typedef __attribute__((ext_vector_type(4))) float f32x4;
typedef __attribute__((ext_vector_type(2))) float f32x2;

static __device__ __forceinline__ float lrelu(float x, float s) { return x > 0.f ? x : s * x; }
static __device__ __forceinline__ unsigned short f2b(float f) {
  union { float f; unsigned int i; } v; v.f = f;
  unsigned int r = (v.i + 0x7fffu + ((v.i >> 16) & 1u)) >> 16;
  return (unsigned short)r;
}
// unpack uint4 (8 bf16) -> 4 float2 pairs
static __device__ __forceinline__ void up2x4(uint4 r, f32x2* v) {
  union { unsigned int i; float f; } t;
  t.i = r.x << 16;          v[0].x = t.f;
  t.i = r.x & 0xffff0000u;  v[0].y = t.f;
  t.i = r.y << 16;          v[1].x = t.f;
  t.i = r.y & 0xffff0000u;  v[1].y = t.f;
  t.i = r.z << 16;          v[2].x = t.f;
  t.i = r.z & 0xffff0000u;  v[2].y = t.f;
  t.i = r.w << 16;          v[3].x = t.f;
  t.i = r.w & 0xffff0000u;  v[3].y = t.f;
}

// ---------------- CSR build ----------------
__global__ void hist_kernel(const int* __restrict__ dst, int* __restrict__ cnt, int E, int N) {
  int i = blockIdx.x * blockDim.x + threadIdx.x;
  int tot = E + N;
  if (i >= tot) return;
  int d = (i < E) ? dst[i] : (i - E);
  atomicAdd(&cnt[d], 1);
}

// two-phase parallel exclusive scan over n counts
__global__ void scan1_kernel(const int* __restrict__ cnt, int* __restrict__ rowptr,
                             int* __restrict__ bsum, int n) {
  __shared__ int wsum[16];
  int t = threadIdx.x, lane = t & 63, wv = t >> 6;
  int i = blockIdx.x * 1024 + t;
  int orig = (i < n) ? cnt[i] : 0;
  int v = orig;
  #pragma unroll
  for (int off = 1; off < 64; off <<= 1) {
    int u = __shfl_up(v, off);
    if (lane >= off) v += u;
  }
  if (lane == 63) wsum[wv] = v;
  __syncthreads();
  if (t < 16) {
    int s = wsum[t];
    #pragma unroll
    for (int off = 1; off < 16; off <<= 1) {
      int u = __shfl_up(s, off);
      if (t >= off) s += u;
    }
    wsum[t] = s;
  }
  __syncthreads();
  int waveoff = (wv > 0) ? wsum[wv - 1] : 0;
  if (i < n) rowptr[i] = waveoff + v - orig;   // exclusive within block
  if (t == 1023) bsum[blockIdx.x] = wsum[15];
}

__global__ void scan2_kernel(int* __restrict__ rowptr, int* __restrict__ cursor,
                             const int* __restrict__ bsum, int n) {
  int t = threadIdx.x, b = blockIdx.x;
  int off = 0;
  for (int k = 0; k < b; ++k) off += bsum[k];
  int i = b * 1024 + t;
  if (i < n) { int e = rowptr[i] + off; rowptr[i] = e; cursor[i] = e; }
  if (b == (int)gridDim.x - 1 && t == 1023) rowptr[n] = off + bsum[b];
}

__global__ void fill_kernel(const int* __restrict__ src, const int* __restrict__ dst,
                            int* __restrict__ cursor, int* __restrict__ colsrc, int E, int N) {
  int i = blockIdx.x * blockDim.x + threadIdx.x;
  int tot = E + N;
  if (i >= tot) return;
  int d, s;
  if (i < E) { d = dst[i]; s = src[i]; } else { d = i - E; s = i - E; }
  int pos = atomicAdd(&cursor[d], 1);
  colsrc[pos] = s;
}

// ---------------- fused prep: transposes + f2b(x) + bias concat + cnt zero ----------
static __device__ __forceinline__ void do_transpose(
    const float* __restrict__ W, unsigned short* __restrict__ Wt,
    int K, int Ncol, int lbid, float (*t)[33]) {
  int nxb = Ncol >> 5;
  int bx = lbid % nxb, by = lbid / nxb;
  int n0 = bx * 32, k0 = by * 32;
  int tx = threadIdx.x & 31, ty = threadIdx.x >> 5;  // ty 0..7
  #pragma unroll
  for (int i = 0; i < 4; ++i)
    t[ty + i * 8][tx] = W[(size_t)(k0 + ty + i * 8) * Ncol + n0 + tx];
  __syncthreads();
  #pragma unroll
  for (int i = 0; i < 4; ++i)
    Wt[(size_t)(n0 + ty + i * 8) * K + k0 + tx] = f2b(t[tx][ty + i * 8]);
}

// block ranges: [0,16) t0 | [16,272) t1 | [272,528) t2 | [528,1552) t3 |
// [1552,2576) t4 | [2576,2832) t5 | [2832,3088) t6 | [3088,3106) bias |
// [3106, 3106+nbf2b) f2b(x) | rest: zero cnt (N ints)
__global__ __launch_bounds__(256) void prep_all(
    const float* __restrict__ W_in,
    const float* __restrict__ Wl1, const float* __restrict__ Wr1,
    const float* __restrict__ Wl2, const float* __restrict__ Wr2,
    const float* __restrict__ Wl3, const float* __restrict__ Wr3,
    unsigned short* __restrict__ WtIn,
    unsigned short* __restrict__ WtL1, unsigned short* __restrict__ WtR1,
    unsigned short* __restrict__ WtL2, unsigned short* __restrict__ WtR2,
    unsigned short* __restrict__ WtL3, unsigned short* __restrict__ WtR3,
    const float* __restrict__ x, unsigned short* __restrict__ xbf, int nx_elems,
    const float* __restrict__ bl1, const float* __restrict__ br1,
    const float* __restrict__ bl2, const float* __restrict__ br2,
    const float* __restrict__ bl3, const float* __restrict__ br3,
    float* __restrict__ bLR1, float* __restrict__ bLR2, float* __restrict__ bLR3,
    int* __restrict__ cnt, int N) {
  __shared__ float t[32][33];
  int bid = blockIdx.x;
  if (bid < 16)        { do_transpose(W_in, WtIn, 64, 256, bid, t); return; }
  if (bid < 272)       { do_transpose(Wl1, WtL1, 256, 1024, bid - 16, t); return; }
  if (bid < 528)       { do_transpose(Wr1, WtR1, 256, 1024, bid - 272, t); return; }
  if (bid < 1552)      { do_transpose(Wl2, WtL2, 1024, 1024, bid - 528, t); return; }
  if (bid < 2576)      { do_transpose(Wr2, WtR2, 1024, 1024, bid - 1552, t); return; }
  if (bid < 2832)      { do_transpose(Wl3, WtL3, 1024, 256, bid - 2576, t); return; }
  if (bid < 3088)      { do_transpose(Wr3, WtR3, 1024, 256, bid - 2832, t); return; }
  if (bid < 3106) {
    int i = (bid - 3088) * 256 + threadIdx.x;   // 0..4607
    if (i < 1024)      bLR1[i] = bl1[i];
    else if (i < 2048) bLR1[i] = br1[i - 1024];
    else if (i < 3072) bLR2[i - 2048] = bl2[i - 2048];
    else if (i < 4096) bLR2[i - 2048] = br2[i - 3072];
    else if (i < 4352) bLR3[i - 4096] = bl3[i - 4096];
    else if (i < 4608) bLR3[i - 4096] = br3[i - 4352];
    return;
  }
  int nbf2b = (nx_elems + 255) / 256;
  if (bid < 3106 + nbf2b) {
    int i = (bid - 3106) * 256 + threadIdx.x;
    if (i < nx_elems) xbf[i] = f2b(x[i]);
    return;
  }
  int i = (bid - 3106 - nbf2b) * 256 + threadIdx.x;
  if (i < N) cnt[i] = 0;
}

// ---------------- bf16 MFMA GEMM: BK=64, register prefetch, 8-chunk XOR swizzle ------
__global__ __launch_bounds__(256) void gemm_mfma(
    const unsigned short* __restrict__ A, const unsigned short* __restrict__ Bt,
    const float* __restrict__ bias, float* __restrict__ Cf, unsigned short* __restrict__ Cb,
    int M, int K, int ldcf, int ldcb, int act) {
  __shared__ __align__(16) unsigned short As[128 * 64];
  __shared__ __align__(16) unsigned short Bs[128 * 64];
  int tid = threadIdx.x;
  int wave = tid >> 6, lane = tid & 63;
  int wm = wave >> 1, wn = wave & 1;
  int quad = lane >> 4, l16 = lane & 15;
  int row0 = blockIdx.y * 128, col0 = blockIdx.x * 128;
  int r0 = tid >> 2, seg0 = tid & 3;
  int f0 = ((r0 & 1) << 2) | ((r0 >> 1) & 3);
  int wsl0 = r0 * 64 + ((seg0 ^ f0) * 8);
  int wsl1 = r0 * 64 + (((seg0 | 4) ^ f0) * 8);
  int wsl2 = wsl0 + 64 * 64;
  int wsl3 = wsl1 + 64 * 64;
  int flane = ((l16 & 1) << 2) | ((l16 >> 1) & 3);

  const unsigned short* gA = A + (size_t)(row0 + r0) * K + seg0 * 8;
  const unsigned short* gB = Bt + (size_t)(col0 + r0) * K + seg0 * 8;
  const size_t rstep = (size_t)64 * K;

  f32x4 acc[4][4];
  #pragma unroll
  for (int i = 0; i < 4; ++i)
    #pragma unroll
    for (int j = 0; j < 4; ++j)
      acc[i][j] = (f32x4){0.f, 0.f, 0.f, 0.f};

  uint4 pa0 = *(const uint4*)(gA);
  uint4 pa1 = *(const uint4*)(gA + 32);
  uint4 pa2 = *(const uint4*)(gA + rstep);
  uint4 pa3 = *(const uint4*)(gA + rstep + 32);
  uint4 pb0 = *(const uint4*)(gB);
  uint4 pb1 = *(const uint4*)(gB + 32);
  uint4 pb2 = *(const uint4*)(gB + rstep);
  uint4 pb3 = *(const uint4*)(gB + rstep + 32);

  for (int k0 = 0; k0 < K; k0 += 64) {
    *(uint4*)&As[wsl0] = pa0;
    *(uint4*)&As[wsl1] = pa1;
    *(uint4*)&As[wsl2] = pa2;
    *(uint4*)&As[wsl3] = pa3;
    *(uint4*)&Bs[wsl0] = pb0;
    *(uint4*)&Bs[wsl1] = pb1;
    *(uint4*)&Bs[wsl2] = pb2;
    *(uint4*)&Bs[wsl3] = pb3;
    __syncthreads();
    int kn = k0 + 64;
    if (kn < K) {
      pa0 = *(const uint4*)(gA + kn);
      pa1 = *(const uint4*)(gA + kn + 32);
      pa2 = *(const uint4*)(gA + kn + rstep);
      pa3 = *(const uint4*)(gA + kn + rstep + 32);
      pb0 = *(const uint4*)(gB + kn);
      pb1 = *(const uint4*)(gB + kn + 32);
      pb2 = *(const uint4*)(gB + kn + rstep);
      pb3 = *(const uint4*)(gB + kn + rstep + 32);
    }
    #pragma unroll
    for (int h = 0; h < 2; ++h) {
      short8 afr[4], bfr[4];
      #pragma unroll
      for (int t = 0; t < 4; ++t) {
        int pcs = (((h << 2) | quad) ^ flane) * 8;
        afr[t] = *(const short8*)&As[(wm * 64 + t * 16 + l16) * 64 + pcs];
        bfr[t] = *(const short8*)&Bs[(wn * 64 + t * 16 + l16) * 64 + pcs];
      }
      #pragma unroll
      for (int mt = 0; mt < 4; ++mt)
        #pragma unroll
        for (int nt = 0; nt < 4; ++nt)
          acc[mt][nt] = __builtin_amdgcn_mfma_f32_16x16x32_bf16(afr[mt], bfr[nt], acc[mt][nt], 0, 0, 0);
    }
    __syncthreads();
  }

  #pragma unroll
  for (int mt = 0; mt < 4; ++mt) {
    #pragma unroll
    for (int r = 0; r < 4; ++r) {
      int row = row0 + wm * 64 + mt * 16 + quad * 4 + r;
      if (row >= M) continue;
      #pragma unroll
      for (int nt = 0; nt < 4; ++nt) {
        int col = col0 + wn * 64 + nt * 16 + l16;
        float v = acc[mt][nt][r] + bias[col];
        if (act == 1) v = lrelu(v, NEG);
        if (Cf) Cf[(size_t)row * ldcf + col] = v;
        if (Cb) Cb[(size_t)row * ldcb + col] = f2b(v);
      }
    }
  }
}

// ---------------- GATv2 aggregation, 4 heads (652-us round-14 form, verbatim) --------
// leaky02(u) = 0.6u + 0.4|u|; loop-invariant xr*0.6a cancels vs the self-center.
__global__ __launch_bounds__(256) void gat_agg_h4(
    const unsigned short* __restrict__ xlr,
    const int* __restrict__ rowptr, const int* __restrict__ colsrc,
    const float* __restrict__ att, const float* __restrict__ bias,
    unsigned short* __restrict__ outb, int n) {
  int d = blockIdx.x;
  if (d >= n) return;
  int hd = threadIdx.x >> 6, ln = threadIdx.x & 63;
  int half = ln >> 5, l32 = ln & 31;
  int cbase = hd * 256 + l32 * 8;
  float a6[8], a4[8];
  f32x2 xr2[4];
  {
    float4 t0 = *(const float4*)(att + cbase);
    float4 t1 = *(const float4*)(att + cbase + 4);
    float a[8] = {t0.x, t0.y, t0.z, t0.w, t1.x, t1.y, t1.z, t1.w};
    #pragma unroll
    for (int c = 0; c < 8; ++c) { a6[c] = 0.6f * a[c]; a4[c] = 0.4f * a[c]; }
    uint4 r = *(const uint4*)(xlr + ((size_t)d << 11) + 1024 + cbase);
    up2x4(r, xr2);
  }
  // self-loop partial score (shared softmax center; xr*a6 term cancels)
  float psp;
  {
    uint4 r = *(const uint4*)(xlr + ((size_t)d << 11) + cbase);
    f32x2 xs[4];
    up2x4(r, xs);
    f32x2 p2 = {0.f, 0.f};
    #pragma unroll
    for (int k = 0; k < 4; ++k) {
      f32x2 u = xs[k] + xr2[k];
      p2.x = fmaf(xs[k].x, a6[2 * k], p2.x);
      p2.x = fmaf(fabsf(u.x), a4[2 * k], p2.x);
      p2.y = fmaf(xs[k].y, a6[2 * k + 1], p2.y);
      p2.y = fmaf(fabsf(u.y), a4[2 * k + 1], p2.y);
    }
    psp = p2.x + p2.y;
    #pragma unroll
    for (int off = 16; off >= 1; off >>= 1) psp += __shfl_xor(psp, off);
  }
  float l = 0.f;
  f32x2 acc2[4];
  #pragma unroll
  for (int k = 0; k < 4; ++k) acc2[k] = (f32x2){0.f, 0.f};
  int beg = rowptr[d], end = rowptr[d + 1];
  for (int j = beg; j < end; j += 4) {
    int j0 = j + half, j1 = j + 2 + half;
    bool v0 = j0 < end, v1 = j1 < end;
    int s0 = colsrc[v0 ? j0 : beg];
    int s1 = colsrc[v1 ? j1 : beg];
    uint4 r0 = *(const uint4*)(xlr + ((size_t)s0 << 11) + cbase);
    uint4 r1 = *(const uint4*)(xlr + ((size_t)s1 << 11) + cbase);
    f32x2 x0[4], x1[4];
    up2x4(r0, x0);
    up2x4(r1, x1);
    float p0 = 0.f, p1 = 0.f;
    #pragma unroll
    for (int k = 0; k < 4; ++k) {
      f32x2 u0 = x0[k] + xr2[k];        // v_pk_add_f32
      f32x2 u1 = x1[k] + xr2[k];
      p0 = fmaf(x0[k].x, a6[2 * k], p0);
      p0 = fmaf(fabsf(u0.x), a4[2 * k], p0);
      p0 = fmaf(x0[k].y, a6[2 * k + 1], p0);
      p0 = fmaf(fabsf(u0.y), a4[2 * k + 1], p0);
      p1 = fmaf(x1[k].x, a6[2 * k], p1);
      p1 = fmaf(fabsf(u1.x), a4[2 * k], p1);
      p1 = fmaf(x1[k].y, a6[2 * k + 1], p1);
      p1 = fmaf(fabsf(u1.y), a4[2 * k + 1], p1);
    }
    #pragma unroll
    for (int off = 16; off >= 1; off >>= 1) {
      p0 += __shfl_xor(p0, off);
      p1 += __shfl_xor(p1, off);
    }
    float w0 = v0 ? __expf(p0 - psp) : 0.f;
    float w1 = v1 ? __expf(p1 - psp) : 0.f;
    l += w0 + w1;
    f32x2 w02 = {w0, w0}, w12 = {w1, w1};
    #pragma unroll
    for (int k = 0; k < 4; ++k) {
      acc2[k] = w02 * x0[k] + acc2[k];  // v_pk_fma_f32
      acc2[k] = w12 * x1[k] + acc2[k];
    }
  }
  // merge halves (shared center -> plain adds)
  l += __shfl_xor(l, 32);
  float inv = 1.f / l;
  float4 b0 = *(const float4*)(bias + cbase);
  float4 b1 = *(const float4*)(bias + cbase + 4);
  float bb[8] = {b0.x, b0.y, b0.z, b0.w, b1.x, b1.y, b1.z, b1.w};
  unsigned int ou[4];
  #pragma unroll
  for (int k = 0; k < 4; ++k) {
    float sx = acc2[k].x + __shfl_xor(acc2[k].x, 32);
    float sy = acc2[k].y + __shfl_xor(acc2[k].y, 32);
    float vx = sx * inv + bb[2 * k];
    float vy = sy * inv + bb[2 * k + 1];
    vx = vx > 0.f ? vx : expm1f(vx);   // ELU
    vy = vy > 0.f ? vy : expm1f(vy);
    ou[k] = (unsigned int)f2b(vx) | ((unsigned int)f2b(vy) << 16);
  }
  if (half == 0) {
    uint4 o = make_uint4(ou[0], ou[1], ou[2], ou[3]);
    *(uint4*)(outb + (size_t)d * 1024 + cbase) = o;
  }
}

// ---------------- fused layer-3 agg + final logits (652-us round-14 form, verbatim) --
__global__ __launch_bounds__(256) void gat_agg_h1_final(
    const unsigned short* __restrict__ xlr,
    const int* __restrict__ rowptr, const int* __restrict__ colsrc,
    const float* __restrict__ att, const float* __restrict__ bias,
    const float* __restrict__ h, const float* __restrict__ Wout,
    const float* __restrict__ bout, float* __restrict__ out, int n) {
  int wv = threadIdx.x >> 6, ln = threadIdx.x & 63;
  int d = blockIdx.x * 4 + wv;
  if (d >= n) return;
  int half = ln >> 5, l32 = ln & 31;
  int c0 = l32 * 8;
  float a6[8], a4[8];
  f32x2 xr2[4];
  {
    float4 t0 = *(const float4*)(att + c0);
    float4 t1 = *(const float4*)(att + c0 + 4);
    float a[8] = {t0.x, t0.y, t0.z, t0.w, t1.x, t1.y, t1.z, t1.w};
    #pragma unroll
    for (int c = 0; c < 8; ++c) { a6[c] = 0.6f * a[c]; a4[c] = 0.4f * a[c]; }
    uint4 r = *(const uint4*)(xlr + ((size_t)d << 9) + 256 + c0);
    up2x4(r, xr2);
  }
  float psp;
  {
    uint4 r = *(const uint4*)(xlr + ((size_t)d << 9) + c0);
    f32x2 xs[4];
    up2x4(r, xs);
    float p = 0.f;
    #pragma unroll
    for (int k = 0; k < 4; ++k) {
      f32x2 u = xs[k] + xr2[k];
      p = fmaf(xs[k].x, a6[2 * k], p);
      p = fmaf(fabsf(u.x), a4[2 * k], p);
      p = fmaf(xs[k].y, a6[2 * k + 1], p);
      p = fmaf(fabsf(u.y), a4[2 * k + 1], p);
    }
    psp = p;
    #pragma unroll
    for (int off = 16; off >= 1; off >>= 1) psp += __shfl_xor(psp, off);
  }
  float l = 0.f;
  f32x2 acc2[4];
  #pragma unroll
  for (int k = 0; k < 4; ++k) acc2[k] = (f32x2){0.f, 0.f};
  int beg = rowptr[d], end = rowptr[d + 1];
  for (int j = beg; j < end; j += 4) {
    int j0 = j + half, j1 = j + 2 + half;
    bool v0 = j0 < end, v1 = j1 < end;
    int s0 = colsrc[v0 ? j0 : beg];
    int s1 = colsrc[v1 ? j1 : beg];
    uint4 r0 = *(const uint4*)(xlr + ((size_t)s0 << 9) + c0);
    uint4 r1 = *(const uint4*)(xlr + ((size_t)s1 << 9) + c0);
    f32x2 x0[4], x1[4];
    up2x4(r0, x0);
    up2x4(r1, x1);
    float p0 = 0.f, p1 = 0.f;
    #pragma unroll
    for (int k = 0; k < 4; ++k) {
      f32x2 u0 = x0[k] + xr2[k];
      f32x2 u1 = x1[k] + xr2[k];
      p0 = fmaf(x0[k].x, a6[2 * k], p0);
      p0 = fmaf(fabsf(u0.x), a4[2 * k], p0);
      p0 = fmaf(x0[k].y, a6[2 * k + 1], p0);
      p0 = fmaf(fabsf(u0.y), a4[2 * k + 1], p0);
      p1 = fmaf(x1[k].x, a6[2 * k], p1);
      p1 = fmaf(fabsf(u1.x), a4[2 * k], p1);
      p1 = fmaf(x1[k].y, a6[2 * k + 1], p1);
      p1 = fmaf(fabsf(u1.y), a4[2 * k + 1], p1);
    }
    #pragma unroll
    for (int off = 16; off >= 1; off >>= 1) {
      p0 += __shfl_xor(p0, off);
      p1 += __shfl_xor(p1, off);
    }
    float w0 = v0 ? __expf(p0 - psp) : 0.f;
    float w1 = v1 ? __expf(p1 - psp) : 0.f;
    l += w0 + w1;
    f32x2 w02 = {w0, w0}, w12 = {w1, w1};
    #pragma unroll
    for (int k = 0; k < 4; ++k) {
      acc2[k] = w02 * x0[k] + acc2[k];
      acc2[k] = w12 * x1[k] + acc2[k];
    }
  }
  l += __shfl_xor(l, 32);
  float inv = 1.f / l;
  float4 b0 = *(const float4*)(bias + c0);
  float4 b1 = *(const float4*)(bias + c0 + 4);
  float bb[8] = {b0.x, b0.y, b0.z, b0.w, b1.x, b1.y, b1.z, b1.w};
  float4 h0 = *(const float4*)(h + (size_t)d * 256 + c0);
  float4 h1v = *(const float4*)(h + (size_t)d * 256 + c0 + 4);
  float hh[8] = {h0.x, h0.y, h0.z, h0.w, h1v.x, h1v.y, h1v.z, h1v.w};
  float4 w0v = *(const float4*)(Wout + c0);
  float4 w1v = *(const float4*)(Wout + c0 + 4);
  float ww[8] = {w0v.x, w0v.y, w0v.z, w0v.w, w1v.x, w1v.y, w1v.z, w1v.w};
  float v = 0.f;
  #pragma unroll
  for (int k = 0; k < 4; ++k) {
    float sx = acc2[k].x + __shfl_xor(acc2[k].x, 32);
    float sy = acc2[k].y + __shfl_xor(acc2[k].y, 32);
    float h3x = sx * inv + bb[2 * k];
    float h3y = sy * inv + bb[2 * k + 1];
    v = fmaf(lrelu(h3x, NEG) + hh[2 * k], ww[2 * k], v);
    v = fmaf(lrelu(h3y, NEG) + hh[2 * k + 1], ww[2 * k + 1], v);
  }
  #pragma unroll
  for (int off = 16; off >= 1; off >>= 1) v += __shfl_xor(v, off);
  if (ln == 0) out[d] = v + bout[0];
}

extern "C" void kernel_launch(void* const* d_in, const int* in_sizes, int n_in,
                              void* d_out, int out_size, void* d_ws, size_t ws_size,
                              hipStream_t stream) {
  const float* x    = (const float*)d_in[0];
  const int*   src  = (const int*)d_in[1];
  const int*   dst  = (const int*)d_in[2];
  const float* W_in = (const float*)d_in[3];
  const float* b_in = (const float*)d_in[4];
  const float* Wl1 = (const float*)d_in[5];  const float* bl1 = (const float*)d_in[6];
  const float* Wr1 = (const float*)d_in[7];  const float* br1 = (const float*)d_in[8];
  const float* att1 = (const float*)d_in[9]; const float* bias1 = (const float*)d_in[10];
  const float* Wl2 = (const float*)d_in[11]; const float* bl2 = (const float*)d_in[12];
  const float* Wr2 = (const float*)d_in[13]; const float* br2 = (const float*)d_in[14];
  const float* att2 = (const float*)d_in[15]; const float* bias2 = (const float*)d_in[16];
  const float* Wl3 = (const float*)d_in[17]; const float* bl3 = (const float*)d_in[18];
  const float* Wr3 = (const float*)d_in[19]; const float* br3 = (const float*)d_in[20];
  const float* att3 = (const float*)d_in[21]; const float* bias3 = (const float*)d_in[22];
  const float* W_out = (const float*)d_in[23]; const float* b_out = (const float*)d_in[24];

  const int N = in_sizes[0] / 64;
  const int E = in_sizes[1];
  const int NP = ((N + 127) / 128) * 128;   // padded rows for GEMM-A buffers
  float* out = (float*)d_out;

  // ---- workspace layout (bf16 xlr; h1/h2 share one buffer; xbf aliases xlr) ----
  char* p = (char*)d_ws;
  float* h    = (float*)p;            p += (size_t)N * 256 * 4;    // fp32 residual
  unsigned short* hbf   = (unsigned short*)p; p += (size_t)NP * 256 * 2;
  unsigned short* h12bf = (unsigned short*)p; p += (size_t)NP * 1024 * 2;
  unsigned short* xlr   = (unsigned short*)p; p += (size_t)N * 2048 * 2;
  unsigned short* WtIn  = (unsigned short*)p; p += (size_t)256 * 64 * 2;
  unsigned short* WtLR1 = (unsigned short*)p; p += (size_t)2048 * 256 * 2;
  unsigned short* WtLR2 = (unsigned short*)p; p += (size_t)2048 * 1024 * 2;
  unsigned short* WtLR3 = (unsigned short*)p; p += (size_t)512 * 1024 * 2;
  float* bLR1 = (float*)p;            p += (size_t)2048 * 4;
  float* bLR2 = (float*)p;            p += (size_t)2048 * 4;
  float* bLR3 = (float*)p;            p += (size_t)512 * 4;
  int* bsum   = (int*)p;              p += (size_t)64 * 4;
  int* cnt    = (int*)p;              p += (size_t)N * 4;
  int* cursor = (int*)p;              p += (size_t)N * 4;
  int* rowptr = (int*)p;              p += (size_t)(N + 1) * 4;
  int* colsrc = (int*)p;
  unsigned short* xbf = xlr;          // alias: dead before first xlr write

  const int tot = E + N;
  dim3 blk(256);

  // fused prep: all transposes + f2b(x) + bias concat + cnt zero in one dispatch
  int nbf2b = (N * 64 + 255) / 256;
  int nz = (N + 255) / 256;
  prep_all<<<3106 + nbf2b + nz, blk, 0, stream>>>(
      W_in, Wl1, Wr1, Wl2, Wr2, Wl3, Wr3,
      WtIn, WtLR1, WtLR1 + (size_t)1024 * 256,
      WtLR2, WtLR2 + (size_t)1024 * 1024,
      WtLR3, WtLR3 + (size_t)256 * 1024,
      x, xbf, N * 64,
      bl1, br1, bl2, br2, bl3, br3, bLR1, bLR2, bLR3,
      cnt, N);

  // CSR build (by dst, self loops appended); two-phase parallel scan
  int nsb = (N + 1023) / 1024;
  hist_kernel<<<(tot + 255) / 256, blk, 0, stream>>>(dst, cnt, E, N);
  scan1_kernel<<<nsb, 1024, 0, stream>>>(cnt, rowptr, bsum, N);
  scan2_kernel<<<nsb, 1024, 0, stream>>>(rowptr, cursor, bsum, N);
  fill_kernel<<<(tot + 255) / 256, blk, 0, stream>>>(src, dst, cursor, colsrc, E, N);

  int gy = NP / 128;
  int gagg4 = N;
  int gagg1 = (N + 3) / 4;

  // h = leaky(x @ W_in + b_in): fp32 h + bf16 hbf   [K=64]
  gemm_mfma<<<dim3(2, gy), blk, 0, stream>>>(xbf, WtIn, b_in, h, hbf, N, 64, 256, 256, 1);

  // layer 1: K=256, fused L|R -> xlr [N,2048] bf16
  gemm_mfma<<<dim3(16, gy), blk, 0, stream>>>(hbf, WtLR1, bLR1, nullptr, xlr, N, 256, 0, 2048, 0);
  gat_agg_h4<<<gagg4, blk, 0, stream>>>(xlr, rowptr, colsrc, att1, bias1, h12bf, N);

  // layer 2: K=1024, fused L|R -> xlr [N,2048] bf16
  gemm_mfma<<<dim3(16, gy), blk, 0, stream>>>(h12bf, WtLR2, bLR2, nullptr, xlr, N, 1024, 0, 2048, 0);
  gat_agg_h4<<<gagg4, blk, 0, stream>>>(xlr, rowptr, colsrc, att2, bias2, h12bf, N);

  // layer 3: K=1024, fused L|R -> xlr [N,512] bf16; agg + residual + logits fused
  gemm_mfma<<<dim3(4, gy), blk, 0, stream>>>(h12bf, WtLR3, bLR3, nullptr, xlr, N, 1024, 0, 512, 0);
  gat_agg_h1_final<<<gagg1, blk, 0, stream>>>(xlr, rowptr, colsrc, att3, bias3,
                                              h, W_out, b_out, out, N);
}